// Round 5
// baseline (2346.694 us; speedup 1.0000x reference)
//
#include <hip/hip_runtime.h>
#include <math.h>

// Problem constants
constexpr int Bn  = 2;
constexpr int CIN = 4;
constexpr int MQn = 1024;
constexpr int D0 = 64, D1 = 32, D2 = 16, D3 = 8;

// Output layout (floats): x [2,128,8,8,8] = 131072, q [1,2,2] = 4, k [3,2] = 6
constexpr int OUT_X = 0;
constexpr int OUT_Q = 131072;
constexpr int OUT_K = 131076;

// Workspace layout (floats). Zero-initialized span first (single memset).
constexpr size_t OFF_CNT   = 0;                    // 6 used
constexpr size_t OFF_ZERO  = 8;                    // zero word for DMA padding
constexpr size_t OFF_D1    = 16;                   // 2*32*32^3
constexpr size_t OFF_T2    = OFF_D1 + 2097152;     // 2*64*16^3
constexpr size_t OFF_D2    = OFF_T2 + 524288;
constexpr size_t OFF_T3    = OFF_D2 + 524288;      // 2*96*8^3
constexpr size_t OFF_D3    = OFF_T3 + 98304;
constexpr size_t ZERO_END  = OFF_D3 + 98304;       // = 3342352
// non-zeroed region
constexpr size_t OFF_SCALE = 3342360;
constexpr size_t OFF_M1    = 3342368;              // 2*32^3
constexpr size_t OFF_M2    = OFF_M1 + 65536;
constexpr size_t OFF_M3    = OFF_M2 + 8192;
constexpr size_t OFF_T1    = OFF_M3 + 1024;        // 2*32*32^3
constexpr size_t OFF_Y1    = OFF_T1 + 2097152;
constexpr size_t OFF_Y2    = OFF_Y1 + 2097152;     // 2*64*16^3
constexpr size_t OFF_Y3    = OFF_Y2 + 524288;      // 2*96*8^3
// transposed weights, layout [chunk][ci][tap][16]
constexpr size_t OFF_W1T   = OFF_Y3 + 98304;
constexpr size_t OFF_G1T   = OFF_W1T + 16000;
constexpr size_t OFF_W2T   = OFF_G1T + 128000;
constexpr size_t OFF_G2T   = OFF_W2T + 256000;
constexpr size_t OFF_W3T   = OFF_G2T + 512000;
constexpr size_t OFF_G3T   = OFF_W3T + 768000;
constexpr size_t OFF_W4T   = OFF_G3T + 1152000;
// end ~12.6M floats (~50.4 MB)

typedef float v4f __attribute__((ext_vector_type(4)));

__device__ __forceinline__ int opaque_zero() {
    int x;
    asm volatile("v_mov_b32 %0, 0" : "=v"(x));
    return x;
}

// Force a VMEM (global_load_dwordx4) load: addrspace(1) cast avoids flat_load.
__device__ __forceinline__ v4f gload4(const v4f* p) {
    return *(const __attribute__((address_space(1))) v4f*)p;
}

__device__ __forceinline__ void async_copy4(const float* g, float* l) {
    __builtin_amdgcn_global_load_lds(
        (const __attribute__((address_space(1))) void*)g,
        (__attribute__((address_space(3))) void*)l, 4, 0, 0);
}

__global__ void qmean_kernel(const float* __restrict__ QF, float* __restrict__ out_q,
                             float* __restrict__ scale) {
    int b = blockIdx.x >> 1, c = blockIdx.x & 1;
    float s = 0.f;
    for (int m = threadIdx.x; m < MQn; m += blockDim.x)
        s += QF[(b * MQn + m) * 2 + c];
    __shared__ float sh[256];
    sh[threadIdx.x] = s;
    __syncthreads();
    for (int st = 128; st > 0; st >>= 1) {
        if (threadIdx.x < st) sh[threadIdx.x] += sh[threadIdx.x + st];
        __syncthreads();
    }
    if (threadIdx.x == 0) {
        float mean = sh[0] / (float)MQn;
        out_q[b * 2 + c] = mean;
        if (c == 0) scale[b] = mean;
    }
}

// Derive m0 from x_feat (any channel nonzero), pool to m1, count c0.
__global__ void mask_pool1_kernel(const float* __restrict__ xf, float* __restrict__ m1,
                                  float* __restrict__ c0) {
    int idx = blockIdx.x * blockDim.x + threadIdx.x;   // 0..65535
    int b = idx >> 15;
    int v = idx & 32767;
    int oz = v >> 10, oy = (v >> 5) & 31, ox = v & 31;
    float cnt = 0.f, mx = 0.f;
    for (int dz = 0; dz < 2; ++dz)
        for (int dy = 0; dy < 2; ++dy)
            for (int dx = 0; dx < 2; ++dx) {
                int z = 2 * oz + dz, y = 2 * oy + dy, x = 2 * ox + dx;
                size_t base = (size_t)b * CIN * D0 * D0 * D0 + ((size_t)z * D0 + y) * D0 + x;
                bool occ = false;
                for (int c = 0; c < CIN; ++c)
                    occ = occ || (xf[base + (size_t)c * D0 * D0 * D0] != 0.f);
                if (occ) { cnt += 1.f; mx = 1.f; }
            }
    m1[idx] = mx;
    __shared__ float sh[256];
    sh[threadIdx.x] = cnt;
    __syncthreads();
    for (int st = 128; st > 0; st >>= 1) {
        if (threadIdx.x < st) sh[threadIdx.x] += sh[threadIdx.x + st];
        __syncthreads();
    }
    if (threadIdx.x == 0) atomicAdd(&c0[b], sh[0]);
}

__global__ void pool_kernel(const float* __restrict__ min_, float* __restrict__ mout,
                            float* __restrict__ cacc, int Din) {
    int Do = Din >> 1;
    int per = Do * Do * Do;
    int idx = blockIdx.x * blockDim.x + threadIdx.x;
    int b = idx / per;
    int v = idx % per;
    int oz = v / (Do * Do), oy = (v / Do) % Do, ox = v % Do;
    float s = 0.f, mx = 0.f;
    for (int dz = 0; dz < 2; ++dz)
        for (int dy = 0; dy < 2; ++dy)
            for (int dx = 0; dx < 2; ++dx) {
                float val = min_[(((size_t)b * Din + 2 * oz + dz) * Din + 2 * oy + dy) * Din + 2 * ox + dx];
                s += val;
                mx = fmaxf(mx, val);
            }
    mout[idx] = mx;
    __shared__ float sh[256];
    sh[threadIdx.x] = s;
    __syncthreads();
    for (int st = 128; st > 0; st >>= 1) {
        if (threadIdx.x < st) sh[threadIdx.x] += sh[threadIdx.x + st];
        __syncthreads();
    }
    if (threadIdx.x == 0) atomicAdd(&cacc[b], sh[0]);
}

__global__ void writek_kernel(const float* __restrict__ cnt, float* __restrict__ outk) {
    int i = threadIdx.x;
    if (i < 6) {
        int row = i >> 1, b = i & 1;  // row0=c2, row1=c1, row2=c0
        float v = (row == 0) ? cnt[4 + b] : (row == 1 ? cnt[2 + b] : cnt[b]);
        outk[i] = v;
    }
}

// Fused transpose of all 7 weight tensors: w[co][ci][tap] -> wt[chunk][ci][tap][j]
// Segment cumulative starts (elements):
constexpr int WS1 = 0,        WE1 = 16000;    // w1  4x32
constexpr int WS2 = 16000,    WE2 = 144000;   // g1  32x32
constexpr int WS3 = 144000,   WE3 = 400000;   // w2  32x64
constexpr int WS4 = 400000,   WE4 = 912000;   // g2  64x64
constexpr int WS5 = 912000,   WE5 = 1680000;  // w3  64x96
constexpr int WS6 = 1680000,  WE6 = 2832000;  // g3  96x96
constexpr int WS7 = 2832000,  WE7 = 4368000;  // w4  96x128
__global__ __launch_bounds__(256) void wtrans_all_kernel(
        const float* __restrict__ w1, const float* __restrict__ g1,
        const float* __restrict__ w2, const float* __restrict__ g2,
        const float* __restrict__ w3, const float* __restrict__ g3,
        const float* __restrict__ w4, float* __restrict__ ws) {
    int idx = blockIdx.x * 256 + threadIdx.x;
    if (idx >= WE7) return;
    const float* src; float* dst; int cin, local;
    if (idx < WE1)      { src = w1; dst = ws + OFF_W1T; cin = 4;  local = idx - WS1; }
    else if (idx < WE2) { src = g1; dst = ws + OFF_G1T; cin = 32; local = idx - WS2; }
    else if (idx < WE3) { src = w2; dst = ws + OFF_W2T; cin = 32; local = idx - WS3; }
    else if (idx < WE4) { src = g2; dst = ws + OFF_G2T; cin = 64; local = idx - WS4; }
    else if (idx < WE5) { src = w3; dst = ws + OFF_W3T; cin = 64; local = idx - WS5; }
    else if (idx < WE6) { src = g3; dst = ws + OFF_G3T; cin = 96; local = idx - WS6; }
    else                { src = w4; dst = ws + OFF_W4T; cin = 96; local = idx - WS7; }
    int per = cin * 125;
    int co = local / per;
    int r  = local % per;
    int ci = r / 125, tap = r % 125;
    int chunk = co >> 4, j = co & 15;
    dst[(((size_t)chunk * cin + ci) * 125 + tap) * 16 + j] = src[local];
}

// Tiled 5x5x5 conv, pad 2. Block = (batch, ci-group, co-chunk, spatial tile 4x8x8).
// Double-buffered LDS data staging via global_load_lds (vmcnt), one barrier per ci.
// Weights: pre-transposed [chunk][ci][tap][16], fetched as broadcast VMEM dwordx4
// (divergent-index trick keeps them off SMEM so lgkmcnt stays pure-DS fine-grained).
// STRIDE==2 uses x-parity-split LDS layout. GDN squares at use.
// CIG==1: full conv epilogue inline. CIG>1: atomicAdd partials.
template<int CINt, int COUTt, int DIN, int DOUT, int STRIDE, bool GDN, int CIG>
__global__ __launch_bounds__(256, 4) void conv_tile_kernel(
    const float* __restrict__ in, const float* __restrict__ wt,
    const float* __restrict__ bb,      // bias (conv CIG==1 only)
    const float* __restrict__ mask,    // conv CIG==1 only
    const float* __restrict__ zerow,   // zero word for padding DMA
    float* __restrict__ out)
{
    constexpr int CO_TILE = 16;
    constexpr int TZ = 4, TY = 8, TX = 8;
    constexpr int LZ = (STRIDE == 1) ? TZ + 4 : 2 * TZ + 3;   // 8 | 11
    constexpr int LY = (STRIDE == 1) ? TY + 4 : 2 * TY + 3;   // 12 | 19
    constexpr int LX = (STRIDE == 1) ? TX + 4 : 2 * TX + 3;   // 12 | 19
    constexpr int LXP = (STRIDE == 2) ? (LX + 1) / 2 : 0;     // 10
    constexpr int ROWLEN = (STRIDE == 2) ? 2 * LXP : LX;      // 20 | 12
    constexpr int LN = LZ * LY * ROWLEN;                      // 1152 | 4180
    constexpr int NLOAD = (LN + 255) / 256;                   // 5 | 17
    constexpr int PADN = NLOAD * 256;
    constexpr int NTZ = DOUT / TZ, NTY = DOUT / TY, NTX = DOUT / TX;
    constexpr int NT = NTZ * NTY * NTX;
    constexpr int NCH = COUTt / CO_TILE;
    constexpr int CIPER = CINt / CIG;
    __shared__ float sh[2][PADN];

    int tile  = blockIdx.x % NT;
    int chunk = (blockIdx.x / NT) % NCH;
    int cig   = (blockIdx.x / (NT * NCH)) % CIG;
    int b     = blockIdx.x / (NT * NCH * CIG);
    int tz0 = (tile / (NTY * NTX)) * TZ;
    int ty0 = ((tile / NTX) % NTY) * TY;
    int tx0 = (tile % NTX) * TX;
    int co0 = chunk * CO_TILE;

    int tid = threadIdx.x;
    int tx = tid & (TX - 1);
    int ty = (tid >> 3) & (TY - 1);
    int tz = tid >> 6;

    int iz0 = tz0 * STRIDE - 2, iy0 = ty0 * STRIDE - 2, ix0 = tx0 * STRIDE - 2;

    // Per-thread staging offsets (same every ci)
    int goff[NLOAD];
#pragma unroll
    for (int k = 0; k < NLOAD; ++k) {
        int i = tid + k * 256;
        int c = i % ROWLEN; int rem = i / ROWLEN;
        int ly = rem % LY, lz = rem / LY;
        int lx;
        if (STRIDE == 2) { int p = c / LXP, xp = c % LXP; lx = 2 * xp + p; }
        else lx = c;
        int gz = iz0 + lz, gy = iy0 + ly, gx = ix0 + lx;
        bool valid = (i < LN) && (lx < LX) &&
                     (unsigned)gz < (unsigned)DIN && (unsigned)gy < (unsigned)DIN &&
                     (unsigned)gx < (unsigned)DIN;
        goff[k] = valid ? ((gz * DIN + gy) * DIN + gx) : -1;
    }

    int ci0 = cig * CIPER;
    auto stage = [&](int ci, int buf) {
        const float* base = in + (size_t)(b * CINt + ci) * DIN * DIN * DIN;
        float* dst = &sh[buf][0];
#pragma unroll
        for (int k = 0; k < NLOAD; ++k) {
            const float* g = (goff[k] >= 0) ? (base + goff[k]) : zerow;
            async_copy4(g, &dst[k * 256 + tid]);
        }
    };

    float acc[CO_TILE];
#pragma unroll
    for (int j = 0; j < CO_TILE; ++j) acc[j] = 0.f;

    int wzero = opaque_zero();   // "divergent" 0 -> weight loads stay VMEM, not SMEM
    const v4f* wt4 = (const v4f*)wt;

    stage(ci0, 0);
#pragma unroll 1
    for (int i = 0; i < CIPER; ++i) {
        int cur = i & 1;
        __syncthreads();                       // drains DMA for buf cur
        if (i + 1 < CIPER) stage(ci0 + i + 1, cur ^ 1);
        const float* shc = &sh[cur][0];
        const v4f* wci = wt4 + (size_t)(chunk * CINt + (ci0 + i)) * 125 * 4 + wzero;
#pragma unroll 1
        for (int kz = 0; kz < 5; ++kz) {
#pragma unroll 1
            for (int ky = 0; ky < 5; ++ky) {
                const float* rp = shc + ((tz * STRIDE + kz) * LY + ty * STRIDE + ky) * ROWLEN + tx;
                const v4f* wrow = wci + (kz * 5 + ky) * 20;
#pragma unroll
                for (int kx = 0; kx < 5; ++kx) {
                    float v = (STRIDE == 2) ? rp[(kx & 1) * LXP + (kx >> 1)] : rp[kx];
                    float vv = GDN ? v * v : v;
#pragma unroll
                    for (int q = 0; q < 4; ++q) {
                        v4f w = gload4(wrow + kx * 4 + q);
                        acc[4 * q + 0] = fmaf(vv, w.x, acc[4 * q + 0]);
                        acc[4 * q + 1] = fmaf(vv, w.y, acc[4 * q + 1]);
                        acc[4 * q + 2] = fmaf(vv, w.z, acc[4 * q + 2]);
                        acc[4 * q + 3] = fmaf(vv, w.w, acc[4 * q + 3]);
                    }
                }
            }
        }
    }

    int z = tz0 + tz, y = ty0 + ty, x = tx0 + tx;
    size_t sp = ((size_t)z * DOUT + y) * DOUT + x;
    if (CIG > 1) {
#pragma unroll
        for (int j = 0; j < CO_TILE; ++j) {
            size_t oidx = (size_t)(b * COUTt + co0 + j) * DOUT * DOUT * DOUT + sp;
            atomicAdd(&out[oidx], acc[j]);
        }
    } else {
        float mval = mask[(size_t)b * DOUT * DOUT * DOUT + sp];
#pragma unroll
        for (int j = 0; j < CO_TILE; ++j) {
            int co = co0 + j;
            size_t oidx = (size_t)(b * COUTt + co) * DOUT * DOUT * DOUT + sp;
            out[oidx] = (acc[j] + bb[co]) * mval;
        }
    }
}

// Epilogues for ci-split partial kernels
template<int COUTt, int DOUT>
__global__ __launch_bounds__(256) void conv_epi_kernel(float* __restrict__ buf,
        const float* __restrict__ bias, const float* __restrict__ mask) {
    constexpr int VOX = DOUT * DOUT * DOUT;
    int idx = blockIdx.x * 256 + threadIdx.x;
    if (idx >= Bn * COUTt * VOX) return;
    int sp = idx % VOX;
    int co = (idx / VOX) % COUTt;
    int b = idx / (VOX * COUTt);
    buf[idx] = (buf[idx] + bias[co]) * mask[b * VOX + sp];
}

template<int COUTt, int DOUT>
__global__ __launch_bounds__(256) void gdn_epi_kernel(const float* __restrict__ t,
        const float* __restrict__ den, const float* __restrict__ beta,
        const float* __restrict__ scale, float* __restrict__ y) {
    constexpr int VOX = DOUT * DOUT * DOUT;
    int idx = blockIdx.x * 256 + threadIdx.x;
    if (idx >= Bn * COUTt * VOX) return;
    int co = (idx / VOX) % COUTt;
    int b = idx / (VOX * COUTt);
    y[idx] = t[idx] * rsqrtf(beta[co] + den[idx]) * scale[b];
}

extern "C" void kernel_launch(void* const* d_in, const int* in_sizes, int n_in,
                              void* d_out, int out_size, void* d_ws, size_t ws_size,
                              hipStream_t stream) {
    const float* x_feat = (const float*)d_in[0];
    const float* QF     = (const float*)d_in[2];
    const float* w1 = (const float*)d_in[3];  const float* b1 = (const float*)d_in[4];
    const float* w2 = (const float*)d_in[5];  const float* b2 = (const float*)d_in[6];
    const float* w3 = (const float*)d_in[7];  const float* b3 = (const float*)d_in[8];
    const float* w4 = (const float*)d_in[9];  const float* b4 = (const float*)d_in[10];
    const float* beta1 = (const float*)d_in[11]; const float* gamma1 = (const float*)d_in[12];
    const float* beta2 = (const float*)d_in[13]; const float* gamma2 = (const float*)d_in[14];
    const float* beta3 = (const float*)d_in[15]; const float* gamma3 = (const float*)d_in[16];

    float* out = (float*)d_out;
    float* ws = (float*)d_ws;
    float* cnt   = ws + OFF_CNT;
    float* zerow = ws + OFF_ZERO;
    float* scale = ws + OFF_SCALE;
    float* m1 = ws + OFF_M1;  float* m2 = ws + OFF_M2;  float* m3 = ws + OFF_M3;
    float* t1 = ws + OFF_T1;  float* d1 = ws + OFF_D1;  float* y1 = ws + OFF_Y1;
    float* t2 = ws + OFF_T2;  float* d2 = ws + OFF_D2;  float* y2 = ws + OFF_Y2;
    float* t3 = ws + OFF_T3;  float* d3 = ws + OFF_D3;  float* y3 = ws + OFF_Y3;
    float* w1T = ws + OFF_W1T; float* g1T = ws + OFF_G1T;
    float* w2T = ws + OFF_W2T; float* g2T = ws + OFF_G2T;
    float* w3T = ws + OFF_W3T; float* g3T = ws + OFF_G3T;
    float* w4T = ws + OFF_W4T;

    // one big memset for cnt/zero/d1/t2/d2/t3/d3, plus the atomic-accumulated output
    hipMemsetAsync(ws, 0, ZERO_END * sizeof(float), stream);
    hipMemsetAsync(out + OUT_X, 0, 131072 * sizeof(float), stream);

    qmean_kernel<<<4, 256, 0, stream>>>(QF, out + OUT_Q, scale);
    mask_pool1_kernel<<<256, 256, 0, stream>>>(x_feat, m1, cnt + 0);
    pool_kernel<<<32, 256, 0, stream>>>(m1, m2, cnt + 2, D1);
    pool_kernel<<<4, 256, 0, stream>>>(m2, m3, cnt + 4, D2);
    writek_kernel<<<1, 64, 0, stream>>>(cnt, out + OUT_K);

    wtrans_all_kernel<<<(WE7 + 255) / 256, 256, 0, stream>>>(
        w1, gamma1, w2, gamma2, w3, gamma3, w4, ws);

    // Stage 1: conv1 (4->32, 64->32, s2, inline epi) + GDN1 (ci-split x2)
    conv_tile_kernel<4, 32, 64, 32, 2, false, 1>
        <<<512, 256, 0, stream>>>(x_feat, w1T, b1, m1, zerow, t1);
    conv_tile_kernel<32, 32, 32, 32, 1, true, 2>
        <<<1024, 256, 0, stream>>>(t1, g1T, nullptr, nullptr, zerow, d1);
    gdn_epi_kernel<32, 32><<<8192, 256, 0, stream>>>(t1, d1, beta1, scale, y1);

    // Stage 2: conv2 (32->64, s2, ci-split x8) + GDN2 (ci-split x8)
    conv_tile_kernel<32, 64, 32, 16, 2, false, 8>
        <<<1024, 256, 0, stream>>>(y1, w2T, nullptr, nullptr, zerow, t2);
    conv_epi_kernel<64, 16><<<2048, 256, 0, stream>>>(t2, b2, m2);
    conv_tile_kernel<64, 64, 16, 16, 1, true, 8>
        <<<1024, 256, 0, stream>>>(t2, g2T, nullptr, nullptr, zerow, d2);
    gdn_epi_kernel<64, 16><<<2048, 256, 0, stream>>>(t2, d2, beta2, scale, y2);

    // Stage 3: conv3 (64->96, s2, ci-split x16) + GDN3 (ci-split x16)
    conv_tile_kernel<64, 96, 16, 8, 2, false, 16>
        <<<384, 256, 0, stream>>>(y2, w3T, nullptr, nullptr, zerow, t3);
    conv_epi_kernel<96, 8><<<384, 256, 0, stream>>>(t3, b3, m3);
    conv_tile_kernel<96, 96, 8, 8, 1, true, 16>
        <<<384, 256, 0, stream>>>(t3, g3T, nullptr, nullptr, zerow, d3);
    gdn_epi_kernel<96, 8><<<384, 256, 0, stream>>>(t3, d3, beta3, scale, y3);

    // Stage 4: conv4 (96->128, s1, ci-split x16) straight to output + epilogue
    conv_tile_kernel<96, 128, 8, 8, 1, false, 16>
        <<<512, 256, 0, stream>>>(y3, w4T, nullptr, nullptr, zerow, out + OUT_X);
    conv_epi_kernel<128, 8><<<512, 256, 0, stream>>>(out + OUT_X, b4, m3);
}

// Round 6
// 787.342 us; speedup vs baseline: 2.9805x; 2.9805x over previous
//
#include <hip/hip_runtime.h>
#include <math.h>

// Problem constants
constexpr int Bn  = 2;
constexpr int CIN = 4;
constexpr int MQn = 1024;
constexpr int D0 = 64, D1 = 32, D2 = 16, D3 = 8;

// Output layout (floats): x [2,128,8,8,8] = 131072, q [1,2,2] = 4, k [3,2] = 6
constexpr int OUT_X = 0;
constexpr int OUT_Q = 131072;
constexpr int OUT_K = 131076;

// Workspace layout (floats). Zero-initialized span first (single memset).
constexpr size_t OFF_CNT   = 0;                    // 6 used
constexpr size_t OFF_ZERO  = 8;                    // 16B zero block for DMA padding
constexpr size_t OFF_D1    = 16;                   // 2*32*32^3
constexpr size_t OFF_T2    = OFF_D1 + 2097152;     // 2*64*16^3
constexpr size_t OFF_D2    = OFF_T2 + 524288;
constexpr size_t OFF_T3    = OFF_D2 + 524288;      // 2*96*8^3
constexpr size_t OFF_D3    = OFF_T3 + 98304;
constexpr size_t ZERO_END  = OFF_D3 + 98304;       // = 3342352
// non-zeroed region
constexpr size_t OFF_SCALE = 3342360;
constexpr size_t OFF_M1    = 3342368;              // 2*32^3
constexpr size_t OFF_M2    = OFF_M1 + 65536;
constexpr size_t OFF_M3    = OFF_M2 + 8192;
constexpr size_t OFF_T1    = OFF_M3 + 1024;        // 2*32*32^3
constexpr size_t OFF_Y1    = OFF_T1 + 2097152;
constexpr size_t OFF_Y2    = OFF_Y1 + 2097152;     // 2*64*16^3
constexpr size_t OFF_Y3    = OFF_Y2 + 524288;      // 2*96*8^3
// transposed weights, layout [chunk][ci][tap][16]
constexpr size_t OFF_W1T   = OFF_Y3 + 98304;
constexpr size_t OFF_G1T   = OFF_W1T + 16000;
constexpr size_t OFF_W2T   = OFF_G1T + 128000;
constexpr size_t OFF_G2T   = OFF_W2T + 256000;
constexpr size_t OFF_W3T   = OFF_G2T + 512000;
constexpr size_t OFF_G3T   = OFF_W3T + 768000;
constexpr size_t OFF_W4T   = OFF_G3T + 1152000;
// end ~12.6M floats (~50.4 MB)

typedef float v4f __attribute__((ext_vector_type(4)));

__device__ __forceinline__ void async_copy4(const float* g, float* l) {
    __builtin_amdgcn_global_load_lds(
        (const __attribute__((address_space(1))) void*)g,
        (__attribute__((address_space(3))) void*)l, 4, 0, 0);
}
__device__ __forceinline__ void async_copy16(const float* g, float* l) {
    __builtin_amdgcn_global_load_lds(
        (const __attribute__((address_space(1))) void*)g,
        (__attribute__((address_space(3))) void*)l, 16, 0, 0);
}

__global__ void qmean_kernel(const float* __restrict__ QF, float* __restrict__ out_q,
                             float* __restrict__ scale) {
    int b = blockIdx.x >> 1, c = blockIdx.x & 1;
    float s = 0.f;
    for (int m = threadIdx.x; m < MQn; m += blockDim.x)
        s += QF[(b * MQn + m) * 2 + c];
    __shared__ float sh[256];
    sh[threadIdx.x] = s;
    __syncthreads();
    for (int st = 128; st > 0; st >>= 1) {
        if (threadIdx.x < st) sh[threadIdx.x] += sh[threadIdx.x + st];
        __syncthreads();
    }
    if (threadIdx.x == 0) {
        float mean = sh[0] / (float)MQn;
        out_q[b * 2 + c] = mean;
        if (c == 0) scale[b] = mean;
    }
}

// Derive m0 from x_feat (any channel nonzero), pool to m1, count c0.
__global__ void mask_pool1_kernel(const float* __restrict__ xf, float* __restrict__ m1,
                                  float* __restrict__ c0) {
    int idx = blockIdx.x * blockDim.x + threadIdx.x;   // 0..65535
    int b = idx >> 15;
    int v = idx & 32767;
    int oz = v >> 10, oy = (v >> 5) & 31, ox = v & 31;
    float cnt = 0.f, mx = 0.f;
    for (int dz = 0; dz < 2; ++dz)
        for (int dy = 0; dy < 2; ++dy)
            for (int dx = 0; dx < 2; ++dx) {
                int z = 2 * oz + dz, y = 2 * oy + dy, x = 2 * ox + dx;
                size_t base = (size_t)b * CIN * D0 * D0 * D0 + ((size_t)z * D0 + y) * D0 + x;
                bool occ = false;
                for (int c = 0; c < CIN; ++c)
                    occ = occ || (xf[base + (size_t)c * D0 * D0 * D0] != 0.f);
                if (occ) { cnt += 1.f; mx = 1.f; }
            }
    m1[idx] = mx;
    __shared__ float sh[256];
    sh[threadIdx.x] = cnt;
    __syncthreads();
    for (int st = 128; st > 0; st >>= 1) {
        if (threadIdx.x < st) sh[threadIdx.x] += sh[threadIdx.x + st];
        __syncthreads();
    }
    if (threadIdx.x == 0) atomicAdd(&c0[b], sh[0]);
}

__global__ void pool_kernel(const float* __restrict__ min_, float* __restrict__ mout,
                            float* __restrict__ cacc, int Din) {
    int Do = Din >> 1;
    int per = Do * Do * Do;
    int idx = blockIdx.x * blockDim.x + threadIdx.x;
    int b = idx / per;
    int v = idx % per;
    int oz = v / (Do * Do), oy = (v / Do) % Do, ox = v % Do;
    float s = 0.f, mx = 0.f;
    for (int dz = 0; dz < 2; ++dz)
        for (int dy = 0; dy < 2; ++dy)
            for (int dx = 0; dx < 2; ++dx) {
                float val = min_[(((size_t)b * Din + 2 * oz + dz) * Din + 2 * oy + dy) * Din + 2 * ox + dx];
                s += val;
                mx = fmaxf(mx, val);
            }
    mout[idx] = mx;
    __shared__ float sh[256];
    sh[threadIdx.x] = s;
    __syncthreads();
    for (int st = 128; st > 0; st >>= 1) {
        if (threadIdx.x < st) sh[threadIdx.x] += sh[threadIdx.x + st];
        __syncthreads();
    }
    if (threadIdx.x == 0) atomicAdd(&cacc[b], sh[0]);
}

__global__ void writek_kernel(const float* __restrict__ cnt, float* __restrict__ outk) {
    int i = threadIdx.x;
    if (i < 6) {
        int row = i >> 1, b = i & 1;  // row0=c2, row1=c1, row2=c0
        float v = (row == 0) ? cnt[4 + b] : (row == 1 ? cnt[2 + b] : cnt[b]);
        outk[i] = v;
    }
}

// Fused transpose of all 7 weight tensors: w[co][ci][tap] -> wt[chunk][ci][tap][j]
constexpr int WS1 = 0,        WE1 = 16000;    // w1  4x32
constexpr int WS2 = 16000,    WE2 = 144000;   // g1  32x32
constexpr int WS3 = 144000,   WE3 = 400000;   // w2  32x64
constexpr int WS4 = 400000,   WE4 = 912000;   // g2  64x64
constexpr int WS5 = 912000,   WE5 = 1680000;  // w3  64x96
constexpr int WS6 = 1680000,  WE6 = 2832000;  // g3  96x96
constexpr int WS7 = 2832000,  WE7 = 4368000;  // w4  96x128
__global__ __launch_bounds__(256) void wtrans_all_kernel(
        const float* __restrict__ w1, const float* __restrict__ g1,
        const float* __restrict__ w2, const float* __restrict__ g2,
        const float* __restrict__ w3, const float* __restrict__ g3,
        const float* __restrict__ w4, float* __restrict__ ws) {
    int idx = blockIdx.x * 256 + threadIdx.x;
    if (idx >= WE7) return;
    const float* src; float* dst; int cin, local;
    if (idx < WE1)      { src = w1; dst = ws + OFF_W1T; cin = 4;  local = idx - WS1; }
    else if (idx < WE2) { src = g1; dst = ws + OFF_G1T; cin = 32; local = idx - WS2; }
    else if (idx < WE3) { src = w2; dst = ws + OFF_W2T; cin = 32; local = idx - WS3; }
    else if (idx < WE4) { src = g2; dst = ws + OFF_G2T; cin = 64; local = idx - WS4; }
    else if (idx < WE5) { src = w3; dst = ws + OFF_W3T; cin = 64; local = idx - WS5; }
    else if (idx < WE6) { src = g3; dst = ws + OFF_G3T; cin = 96; local = idx - WS6; }
    else                { src = w4; dst = ws + OFF_W4T; cin = 96; local = idx - WS7; }
    int per = cin * 125;
    int co = local / per;
    int r  = local % per;
    int ci = r / 125, tap = r % 125;
    int chunk = co >> 4, j = co & 15;
    dst[(((size_t)chunk * cin + ci) * 125 + tap) * 16 + j] = src[local];
}

// Tiled 5x5x5 conv, pad 2. Block = (batch, ci-group, co-chunk, spatial tile).
// Data AND per-ci weight slab (125x16 fl = 8KB) double-buffered in LDS via
// global_load_lds; one barrier per ci. Inner loop is DS-only: divergent
// ds_read_b32 for data + uniform (broadcast) ds_read_b128 for weights.
// STRIDE==1: each thread computes 2 voxels (VO=2, 8x8x8 tile).
// STRIDE==2: 1 voxel (4x8x8 tile), x-parity-split LDS layout.
// GDN squares at use. CIG==1: inline conv epilogue. CIG>1: atomicAdd partials.
template<int CINt, int COUTt, int DIN, int DOUT, int STRIDE, bool GDN, int CIG>
__global__ __launch_bounds__(256, 4) void conv_tile_kernel(
    const float* __restrict__ in, const float* __restrict__ wt,
    const float* __restrict__ bb,      // bias (conv CIG==1 only)
    const float* __restrict__ mask,    // conv CIG==1 only
    const float* __restrict__ zerow,   // 16B zero block for padding DMA
    float* __restrict__ out)
{
    constexpr int VO = (STRIDE == 1) ? 2 : 1;
    constexpr int TZO = (STRIDE == 1) ? 8 : 4;      // output z-extent of tile
    constexpr int TY = 8, TX = 8;
    constexpr int LZ = (STRIDE == 1) ? TZO + 4 : 2 * TZO + 3;  // 12 | 11
    constexpr int LY = (STRIDE == 1) ? TY + 4 : 2 * TY + 3;    // 12 | 19
    constexpr int LX = (STRIDE == 1) ? TX + 4 : 2 * TX + 3;    // 12 | 19
    constexpr int LXP = (STRIDE == 2) ? (LX + 1) / 2 : 0;      // 10
    constexpr int ROWLEN = (STRIDE == 2) ? 2 * LXP : LX;       // 20 | 12
    constexpr int LN = LZ * LY * ROWLEN;                       // 1728 | 4180
    constexpr int NLOAD = (LN + 255) / 256;                    // 7 | 17
    constexpr int PADN = NLOAD * 256;
    constexpr int NTZ = DOUT / TZO, NTY = DOUT / TY, NTX = DOUT / TX;
    constexpr int NT = NTZ * NTY * NTX;
    constexpr int NCH = COUTt / 16;
    constexpr int CIPER = CINt / CIG;
    __shared__ float sh[2][PADN];
    __shared__ float wbuf[2][2048];                 // 125*16=2000 used

    int tile  = blockIdx.x % NT;
    int chunk = (blockIdx.x / NT) % NCH;
    int cig   = (blockIdx.x / (NT * NCH)) % CIG;
    int b     = blockIdx.x / (NT * NCH * CIG);
    int tz0 = (tile / (NTY * NTX)) * TZO;
    int ty0 = ((tile / NTX) % NTY) * TY;
    int tx0 = (tile % NTX) * TX;
    int co0 = chunk * 16;

    int tid = threadIdx.x;
    int tx = tid & (TX - 1);
    int ty = (tid >> 3) & (TY - 1);
    int tz = tid >> 6;                              // 0..3

    int iz0 = tz0 * STRIDE - 2, iy0 = ty0 * STRIDE - 2, ix0 = tx0 * STRIDE - 2;

    // Per-thread data staging offsets (same every ci)
    int goff[NLOAD];
#pragma unroll
    for (int k = 0; k < NLOAD; ++k) {
        int i = tid + k * 256;
        int c = i % ROWLEN; int rem = i / ROWLEN;
        int ly = rem % LY, lz = rem / LY;
        int lx;
        if (STRIDE == 2) { int p = c / LXP, xp = c % LXP; lx = 2 * xp + p; }
        else lx = c;
        int gz = iz0 + lz, gy = iy0 + ly, gx = ix0 + lx;
        bool valid = (i < LN) && (lx < LX) &&
                     (unsigned)gz < (unsigned)DIN && (unsigned)gy < (unsigned)DIN &&
                     (unsigned)gx < (unsigned)DIN;
        goff[k] = valid ? ((gz * DIN + gy) * DIN + gx) : -1;
    }

    int ci0 = cig * CIPER;
    auto stage = [&](int ci, int buf) {
        const float* base = in + (size_t)(b * CINt + ci) * DIN * DIN * DIN;
        float* dst = &sh[buf][0];
#pragma unroll
        for (int k = 0; k < NLOAD; ++k) {
            const float* g = (goff[k] >= 0) ? (base + goff[k]) : zerow;
            async_copy4(g, &dst[k * 256 + tid]);
        }
        // weight slab: 2000 contiguous floats, width-16 DMA (lane=16B)
        const float* wsrc = wt + (size_t)(chunk * CINt + ci) * 2000;
#pragma unroll
        for (int k = 0; k < 2; ++k) {
            int f0 = (k * 256 + tid) * 4;
            const float* g = (f0 < 2000) ? (wsrc + f0) : zerow;
            async_copy16(g, &wbuf[buf][f0]);
        }
    };

    float acc[VO][16];
#pragma unroll
    for (int v = 0; v < VO; ++v)
#pragma unroll
        for (int j = 0; j < 16; ++j) acc[v][j] = 0.f;

    stage(ci0, 0);
#pragma unroll 1
    for (int i = 0; i < CIPER; ++i) {
        int cur = i & 1;
        __syncthreads();                       // drains DMA for buf cur
        if (i + 1 < CIPER) stage(ci0 + i + 1, cur ^ 1);
        const float* shc = &sh[cur][0];
        const float* wb = &wbuf[cur][0];
#pragma unroll 1
        for (int kz = 0; kz < 5; ++kz) {
#pragma unroll 1
            for (int ky = 0; ky < 5; ++ky) {
                const float* rp = shc + ((tz * STRIDE + kz) * LY + ty * STRIDE + ky) * ROWLEN + tx;
                const float* wrow = wb + (kz * 5 + ky) * 5 * 16;
#pragma unroll
                for (int kx = 0; kx < 5; ++kx) {
                    float vv[VO];
#pragma unroll
                    for (int v = 0; v < VO; ++v) {
                        float d = (STRIDE == 2)
                                  ? rp[(kx & 1) * LXP + (kx >> 1)]
                                  : rp[kx + v * 4 * LY * ROWLEN];
                        vv[v] = GDN ? d * d : d;
                    }
#pragma unroll
                    for (int q = 0; q < 4; ++q) {
                        v4f w = *(const v4f*)&wrow[kx * 16 + q * 4];
#pragma unroll
                        for (int v = 0; v < VO; ++v) {
                            acc[v][4 * q + 0] = fmaf(vv[v], w.x, acc[v][4 * q + 0]);
                            acc[v][4 * q + 1] = fmaf(vv[v], w.y, acc[v][4 * q + 1]);
                            acc[v][4 * q + 2] = fmaf(vv[v], w.z, acc[v][4 * q + 2]);
                            acc[v][4 * q + 3] = fmaf(vv[v], w.w, acc[v][4 * q + 3]);
                        }
                    }
                }
            }
        }
    }

    int y = ty0 + ty, x = tx0 + tx;
#pragma unroll
    for (int v = 0; v < VO; ++v) {
        int z = tz0 + tz + v * 4;
        size_t sp = ((size_t)z * DOUT + y) * DOUT + x;
        if (CIG > 1) {
#pragma unroll
            for (int j = 0; j < 16; ++j) {
                size_t oidx = (size_t)(b * COUTt + co0 + j) * DOUT * DOUT * DOUT + sp;
                atomicAdd(&out[oidx], acc[v][j]);
            }
        } else {
            float mval = mask[(size_t)b * DOUT * DOUT * DOUT + sp];
#pragma unroll
            for (int j = 0; j < 16; ++j) {
                int co = co0 + j;
                size_t oidx = (size_t)(b * COUTt + co) * DOUT * DOUT * DOUT + sp;
                out[oidx] = (acc[v][j] + bb[co]) * mval;
            }
        }
    }
}

// Epilogues for ci-split partial kernels
template<int COUTt, int DOUT>
__global__ __launch_bounds__(256) void conv_epi_kernel(float* __restrict__ buf,
        const float* __restrict__ bias, const float* __restrict__ mask) {
    constexpr int VOX = DOUT * DOUT * DOUT;
    int idx = blockIdx.x * 256 + threadIdx.x;
    if (idx >= Bn * COUTt * VOX) return;
    int sp = idx % VOX;
    int co = (idx / VOX) % COUTt;
    int b = idx / (VOX * COUTt);
    buf[idx] = (buf[idx] + bias[co]) * mask[b * VOX + sp];
}

template<int COUTt, int DOUT>
__global__ __launch_bounds__(256) void gdn_epi_kernel(const float* __restrict__ t,
        const float* __restrict__ den, const float* __restrict__ beta,
        const float* __restrict__ scale, float* __restrict__ y) {
    constexpr int VOX = DOUT * DOUT * DOUT;
    int idx = blockIdx.x * 256 + threadIdx.x;
    if (idx >= Bn * COUTt * VOX) return;
    int co = (idx / VOX) % COUTt;
    int b = idx / (VOX * COUTt);
    y[idx] = t[idx] * rsqrtf(beta[co] + den[idx]) * scale[b];
}

extern "C" void kernel_launch(void* const* d_in, const int* in_sizes, int n_in,
                              void* d_out, int out_size, void* d_ws, size_t ws_size,
                              hipStream_t stream) {
    const float* x_feat = (const float*)d_in[0];
    const float* QF     = (const float*)d_in[2];
    const float* w1 = (const float*)d_in[3];  const float* b1 = (const float*)d_in[4];
    const float* w2 = (const float*)d_in[5];  const float* b2 = (const float*)d_in[6];
    const float* w3 = (const float*)d_in[7];  const float* b3 = (const float*)d_in[8];
    const float* w4 = (const float*)d_in[9];  const float* b4 = (const float*)d_in[10];
    const float* beta1 = (const float*)d_in[11]; const float* gamma1 = (const float*)d_in[12];
    const float* beta2 = (const float*)d_in[13]; const float* gamma2 = (const float*)d_in[14];
    const float* beta3 = (const float*)d_in[15]; const float* gamma3 = (const float*)d_in[16];

    float* out = (float*)d_out;
    float* ws = (float*)d_ws;
    float* cnt   = ws + OFF_CNT;
    float* zerow = ws + OFF_ZERO;
    float* scale = ws + OFF_SCALE;
    float* m1 = ws + OFF_M1;  float* m2 = ws + OFF_M2;  float* m3 = ws + OFF_M3;
    float* t1 = ws + OFF_T1;  float* d1 = ws + OFF_D1;  float* y1 = ws + OFF_Y1;
    float* t2 = ws + OFF_T2;  float* d2 = ws + OFF_D2;  float* y2 = ws + OFF_Y2;
    float* t3 = ws + OFF_T3;  float* d3 = ws + OFF_D3;  float* y3 = ws + OFF_Y3;
    float* w1T = ws + OFF_W1T; float* g1T = ws + OFF_G1T;
    float* w2T = ws + OFF_W2T; float* g2T = ws + OFF_G2T;
    float* w3T = ws + OFF_W3T; float* g3T = ws + OFF_G3T;
    float* w4T = ws + OFF_W4T;

    hipMemsetAsync(ws, 0, ZERO_END * sizeof(float), stream);
    hipMemsetAsync(out + OUT_X, 0, 131072 * sizeof(float), stream);

    qmean_kernel<<<4, 256, 0, stream>>>(QF, out + OUT_Q, scale);
    mask_pool1_kernel<<<256, 256, 0, stream>>>(x_feat, m1, cnt + 0);
    pool_kernel<<<32, 256, 0, stream>>>(m1, m2, cnt + 2, D1);
    pool_kernel<<<4, 256, 0, stream>>>(m2, m3, cnt + 4, D2);
    writek_kernel<<<1, 64, 0, stream>>>(cnt, out + OUT_K);

    wtrans_all_kernel<<<(WE7 + 255) / 256, 256, 0, stream>>>(
        w1, gamma1, w2, gamma2, w3, gamma3, w4, ws);

    // Stage 1: conv1 (4->32, 64->32, s2, inline epi) + GDN1 (ci-split x4)
    conv_tile_kernel<4, 32, 64, 32, 2, false, 1>
        <<<512, 256, 0, stream>>>(x_feat, w1T, b1, m1, zerow, t1);
    conv_tile_kernel<32, 32, 32, 32, 1, true, 4>
        <<<1024, 256, 0, stream>>>(t1, g1T, nullptr, nullptr, zerow, d1);
    gdn_epi_kernel<32, 32><<<8192, 256, 0, stream>>>(t1, d1, beta1, scale, y1);

    // Stage 2: conv2 (32->64, s2, ci-split x8) + GDN2 (ci-split x16)
    conv_tile_kernel<32, 64, 32, 16, 2, false, 8>
        <<<1024, 256, 0, stream>>>(y1, w2T, nullptr, nullptr, zerow, t2);
    conv_epi_kernel<64, 16><<<2048, 256, 0, stream>>>(t2, b2, m2);
    conv_tile_kernel<64, 64, 16, 16, 1, true, 16>
        <<<1024, 256, 0, stream>>>(t2, g2T, nullptr, nullptr, zerow, d2);
    gdn_epi_kernel<64, 16><<<2048, 256, 0, stream>>>(t2, d2, beta2, scale, y2);

    // Stage 3: conv3 (64->96, s2, ci-split x8) + GDN3 (ci-split x16)
    conv_tile_kernel<64, 96, 16, 8, 2, false, 8>
        <<<192, 256, 0, stream>>>(y2, w3T, nullptr, nullptr, zerow, t3);
    conv_epi_kernel<96, 8><<<384, 256, 0, stream>>>(t3, b3, m3);
    conv_tile_kernel<96, 96, 8, 8, 1, true, 16>
        <<<192, 256, 0, stream>>>(t3, g3T, nullptr, nullptr, zerow, d3);
    gdn_epi_kernel<96, 8><<<384, 256, 0, stream>>>(t3, d3, beta3, scale, y3);

    // Stage 4: conv4 (96->128, s1, ci-split x16) straight to output + epilogue
    conv_tile_kernel<96, 128, 8, 8, 1, false, 16>
        <<<256, 256, 0, stream>>>(y3, w4T, nullptr, nullptr, zerow, out + OUT_X);
    conv_epi_kernel<128, 8><<<512, 256, 0, stream>>>(out + OUT_X, b4, m3);
}

// Round 7
// 494.671 us; speedup vs baseline: 4.7440x; 1.5916x over previous
//
#include <hip/hip_runtime.h>
#include <math.h>

// Problem constants
constexpr int Bn  = 2;
constexpr int CIN = 4;
constexpr int MQn = 1024;
constexpr int D0 = 64, D1 = 32, D2 = 16, D3 = 8;

// Output layout (floats): x [2,128,8,8,8] = 131072, q [1,2,2] = 4, k [3,2] = 6
constexpr int OUT_X = 0;
constexpr int OUT_Q = 131072;
constexpr int OUT_K = 131076;

// Workspace layout (floats). Zero-initialized span first (single memset).
constexpr size_t OFF_CNT   = 0;
constexpr size_t OFF_ZERO  = 8;                    // 32B zero block for DMA padding
constexpr size_t OFF_D1    = 16;                   // 2*32*32^3
constexpr size_t OFF_T2    = OFF_D1 + 2097152;     // 2*64*16^3
constexpr size_t OFF_D2    = OFF_T2 + 524288;
constexpr size_t OFF_T3    = OFF_D2 + 524288;      // 2*96*8^3
constexpr size_t OFF_D3    = OFF_T3 + 98304;
constexpr size_t ZERO_END  = OFF_D3 + 98304;       // 3342352
// non-zeroed region
constexpr size_t OFF_SCALE = 3342360;
constexpr size_t OFF_M1    = 3342368;              // 2*32^3
constexpr size_t OFF_M2    = OFF_M1 + 65536;
constexpr size_t OFF_M3    = OFF_M2 + 8192;
constexpr size_t OFF_T1    = OFF_M3 + 1024;        // 2*32*32^3
constexpr size_t OFF_Y1    = OFF_T1 + 2097152;
constexpr size_t OFF_Y2    = OFF_Y1 + 2097152;     // 2*64*16^3
// channel-last bf16 buffers (sizes in floats = shorts/2)
constexpr size_t OFF_SQ1   = OFF_Y2 + 524288;      // 2*32^3*32 sh = 1048576 fl
constexpr size_t OFF_SQ2   = OFF_SQ1 + 1048576;    // 2*16^3*64 sh = 262144 fl
constexpr size_t OFF_SQ3   = OFF_SQ2 + 262144;     // 2*8^3*96 sh = 49152 fl
constexpr size_t OFF_Y3C   = OFF_SQ3 + 49152;      // 2*8^3*96 sh = 49152 fl
// fp32 transposed weights for VALU convs [chunk][ci][tap][16]
constexpr size_t OFF_W1T   = OFF_Y3C + 49152;      // 16000
constexpr size_t OFF_W2T   = OFF_W1T + 16000;      // 256000
constexpr size_t OFF_W3T   = OFF_W2T + 256000;     // 768000
// bf16 MFMA weights [cs][nch][tap][n32][kc2][8]
constexpr size_t OFF_WB1   = OFF_W3T + 768000;     // 128000 sh = 64000 fl
constexpr size_t OFF_WB2   = OFF_WB1 + 64000;      // 512000 sh = 256000 fl
constexpr size_t OFF_WB3   = OFF_WB2 + 256000;     // 1152000 sh = 576000 fl
constexpr size_t OFF_WB4   = OFF_WB3 + 576000;     // 1536000 sh = 768000 fl
// end = 12248736 floats (~49 MB)

typedef float v4f __attribute__((ext_vector_type(4)));
typedef __attribute__((ext_vector_type(8)))  short bf16x8v;
typedef __attribute__((ext_vector_type(16))) float f32x16v;

__device__ __forceinline__ void async_copy4(const float* g, float* l) {
    __builtin_amdgcn_global_load_lds(
        (const __attribute__((address_space(1))) void*)g,
        (__attribute__((address_space(3))) void*)l, 4, 0, 0);
}
__device__ __forceinline__ void async_copy16(const float* g, float* l) {
    __builtin_amdgcn_global_load_lds(
        (const __attribute__((address_space(1))) void*)g,
        (__attribute__((address_space(3))) void*)l, 16, 0, 0);
}
__device__ __forceinline__ unsigned short f2bf(float f) {
    unsigned u = __float_as_uint(f);
    return (unsigned short)((u + 0x7FFFu + ((u >> 16) & 1u)) >> 16);
}

__global__ void qmean_kernel(const float* __restrict__ QF, float* __restrict__ out_q,
                             float* __restrict__ scale) {
    int b = blockIdx.x >> 1, c = blockIdx.x & 1;
    float s = 0.f;
    for (int m = threadIdx.x; m < MQn; m += blockDim.x)
        s += QF[(b * MQn + m) * 2 + c];
    __shared__ float sh[256];
    sh[threadIdx.x] = s;
    __syncthreads();
    for (int st = 128; st > 0; st >>= 1) {
        if (threadIdx.x < st) sh[threadIdx.x] += sh[threadIdx.x + st];
        __syncthreads();
    }
    if (threadIdx.x == 0) {
        float mean = sh[0] / (float)MQn;
        out_q[b * 2 + c] = mean;
        if (c == 0) scale[b] = mean;
    }
}

__global__ void mask_pool1_kernel(const float* __restrict__ xf, float* __restrict__ m1,
                                  float* __restrict__ c0) {
    int idx = blockIdx.x * blockDim.x + threadIdx.x;   // 0..65535
    int b = idx >> 15;
    int v = idx & 32767;
    int oz = v >> 10, oy = (v >> 5) & 31, ox = v & 31;
    float cnt = 0.f, mx = 0.f;
    for (int dz = 0; dz < 2; ++dz)
        for (int dy = 0; dy < 2; ++dy)
            for (int dx = 0; dx < 2; ++dx) {
                int z = 2 * oz + dz, y = 2 * oy + dy, x = 2 * ox + dx;
                size_t base = (size_t)b * CIN * D0 * D0 * D0 + ((size_t)z * D0 + y) * D0 + x;
                bool occ = false;
                for (int c = 0; c < CIN; ++c)
                    occ = occ || (xf[base + (size_t)c * D0 * D0 * D0] != 0.f);
                if (occ) { cnt += 1.f; mx = 1.f; }
            }
    m1[idx] = mx;
    __shared__ float sh[256];
    sh[threadIdx.x] = cnt;
    __syncthreads();
    for (int st = 128; st > 0; st >>= 1) {
        if (threadIdx.x < st) sh[threadIdx.x] += sh[threadIdx.x + st];
        __syncthreads();
    }
    if (threadIdx.x == 0) atomicAdd(&c0[b], sh[0]);
}

__global__ void pool_kernel(const float* __restrict__ min_, float* __restrict__ mout,
                            float* __restrict__ cacc, int Din) {
    int Do = Din >> 1;
    int per = Do * Do * Do;
    int idx = blockIdx.x * blockDim.x + threadIdx.x;
    int b = idx / per;
    int v = idx % per;
    int oz = v / (Do * Do), oy = (v / Do) % Do, ox = v % Do;
    float s = 0.f, mx = 0.f;
    for (int dz = 0; dz < 2; ++dz)
        for (int dy = 0; dy < 2; ++dy)
            for (int dx = 0; dx < 2; ++dx) {
                float val = min_[(((size_t)b * Din + 2 * oz + dz) * Din + 2 * oy + dy) * Din + 2 * ox + dx];
                s += val;
                mx = fmaxf(mx, val);
            }
    mout[idx] = mx;
    __shared__ float sh[256];
    sh[threadIdx.x] = s;
    __syncthreads();
    for (int st = 128; st > 0; st >>= 1) {
        if (threadIdx.x < st) sh[threadIdx.x] += sh[threadIdx.x + st];
        __syncthreads();
    }
    if (threadIdx.x == 0) atomicAdd(&cacc[b], sh[0]);
}

__global__ void writek_kernel(const float* __restrict__ cnt, float* __restrict__ outk) {
    int i = threadIdx.x;
    if (i < 6) {
        int row = i >> 1, b = i & 1;
        float v = (row == 0) ? cnt[4 + b] : (row == 1 ? cnt[2 + b] : cnt[b]);
        outk[i] = v;
    }
}

// fp32 transpose for VALU convs: w[co][ci][tap] -> [chunk][ci][tap][16]
constexpr int FS1 = 0,       FE1 = 16000;     // w1 4x32
constexpr int FS2 = 16000,   FE2 = 272000;    // w2 32x64
constexpr int FS3 = 272000,  FE3 = 1040000;   // w3 64x96
__global__ __launch_bounds__(256) void wtrans_all_kernel(
        const float* __restrict__ w1, const float* __restrict__ w2,
        const float* __restrict__ w3, float* __restrict__ ws) {
    int idx = blockIdx.x * 256 + threadIdx.x;
    if (idx >= FE3) return;
    const float* src; float* dst; int cin, local;
    if (idx < FE1)      { src = w1; dst = ws + OFF_W1T; cin = 4;  local = idx - FS1; }
    else if (idx < FE2) { src = w2; dst = ws + OFF_W2T; cin = 32; local = idx - FS2; }
    else                { src = w3; dst = ws + OFF_W3T; cin = 64; local = idx - FS3; }
    int per = cin * 125;
    int co = local / per;
    int r  = local % per;
    int ci = r / 125, tap = r % 125;
    int chunk = co >> 4, j = co & 15;
    dst[(((size_t)chunk * cin + ci) * 125 + tap) * 16 + j] = src[local];
}

// bf16 MFMA weight transform: w[co][ci][tap] fp32 -> [cs][nch][tap][n32][kc2][8] bf16
constexpr int MS1 = 0,        ME1 = 128000;   // gamma1 NCH1 CIN32
constexpr int MS2 = 128000,   ME2 = 640000;   // gamma2 NCH2 CIN64
constexpr int MS3 = 640000,   ME3 = 1792000;  // gamma3 NCH3 CIN96
constexpr int MS4 = 1792000,  ME4 = 3328000;  // w4     NCH4 CIN96
__global__ __launch_bounds__(256) void mwtrans_all_kernel(
        const float* __restrict__ g1, const float* __restrict__ g2,
        const float* __restrict__ g3, const float* __restrict__ w4,
        float* __restrict__ ws) {
    int idx = blockIdx.x * 256 + threadIdx.x;
    if (idx >= ME4) return;
    const float* src; unsigned short* dst; int nchn, cin, o;
    if (idx < ME1)      { src = g1; dst = (unsigned short*)(ws + OFF_WB1); nchn = 1; cin = 32; o = idx - MS1; }
    else if (idx < ME2) { src = g2; dst = (unsigned short*)(ws + OFF_WB2); nchn = 2; cin = 64; o = idx - MS2; }
    else if (idx < ME3) { src = g3; dst = (unsigned short*)(ws + OFF_WB3); nchn = 3; cin = 96; o = idx - MS3; }
    else                { src = w4; dst = (unsigned short*)(ws + OFF_WB4); nchn = 4; cin = 96; o = idx - MS4; }
    int j  = o & 7;
    int kc = (o >> 3) & 1;
    int n  = (o >> 4) & 31;
    int q  = o >> 9;
    int tap = q % 125;
    int q2  = q / 125;
    int nch = q2 % nchn;
    int cs  = q2 / nchn;
    int co = nch * 32 + n;
    int ci = cs * 16 + kc * 8 + j;
    dst[o] = f2bf(src[((size_t)co * cin + ci) * 125 + tap]);
}

// ===== VALU tiled conv (stride-2 convs 1/2/3), proven R5 structure =====
template<int CINt, int COUTt, int DIN, int DOUT, int STRIDE, int CIG, bool SQW>
__global__ __launch_bounds__(256, 4) void conv_tile_kernel(
    const float* __restrict__ in, const float* __restrict__ wt,
    const float* __restrict__ bb, const float* __restrict__ mask,
    const float* __restrict__ zerow, float* __restrict__ out,
    unsigned short* __restrict__ sqcl)
{
    constexpr int TZO = 4, TY = 8, TX = 8;
    constexpr int LZ = (STRIDE == 1) ? TZO + 4 : 2 * TZO + 3;
    constexpr int LY = (STRIDE == 1) ? TY + 4 : 2 * TY + 3;
    constexpr int LX = (STRIDE == 1) ? TX + 4 : 2 * TX + 3;
    constexpr int LXP = (STRIDE == 2) ? (LX + 1) / 2 : 0;
    constexpr int ROWLEN = (STRIDE == 2) ? 2 * LXP : LX;
    constexpr int LN = LZ * LY * ROWLEN;
    constexpr int NLOAD = (LN + 255) / 256;
    constexpr int PADN = NLOAD * 256;
    constexpr int NTZ = DOUT / TZO, NTY = DOUT / TY, NTX = DOUT / TX;
    constexpr int NT = NTZ * NTY * NTX;
    constexpr int NCHk = COUTt / 16;
    constexpr int CIPER = CINt / CIG;
    __shared__ float sh[2][PADN];
    __shared__ float wbuf[2][2048];

    int tile  = blockIdx.x % NT;
    int chunk = (blockIdx.x / NT) % NCHk;
    int cig   = (blockIdx.x / (NT * NCHk)) % CIG;
    int b     = blockIdx.x / (NT * NCHk * CIG);
    int tz0 = (tile / (NTY * NTX)) * TZO;
    int ty0 = ((tile / NTX) % NTY) * TY;
    int tx0 = (tile % NTX) * TX;
    int co0 = chunk * 16;

    int tid = threadIdx.x;
    int tx = tid & (TX - 1);
    int ty = (tid >> 3) & (TY - 1);
    int tz = tid >> 6;

    int iz0 = tz0 * STRIDE - 2, iy0 = ty0 * STRIDE - 2, ix0 = tx0 * STRIDE - 2;

    int goff[NLOAD];
#pragma unroll
    for (int k = 0; k < NLOAD; ++k) {
        int i = tid + k * 256;
        int c = i % ROWLEN; int rem = i / ROWLEN;
        int ly = rem % LY, lz = rem / LY;
        int lx;
        if (STRIDE == 2) { int p = c / LXP, xp = c % LXP; lx = 2 * xp + p; }
        else lx = c;
        int gz = iz0 + lz, gy = iy0 + ly, gx = ix0 + lx;
        bool valid = (i < LN) && (lx < LX) &&
                     (unsigned)gz < (unsigned)DIN && (unsigned)gy < (unsigned)DIN &&
                     (unsigned)gx < (unsigned)DIN;
        goff[k] = valid ? ((gz * DIN + gy) * DIN + gx) : -1;
    }

    int ci0 = cig * CIPER;
    auto stage = [&](int ci, int buf) {
        const float* base = in + (size_t)(b * CINt + ci) * DIN * DIN * DIN;
        float* dst = &sh[buf][0];
#pragma unroll
        for (int k = 0; k < NLOAD; ++k) {
            const float* g = (goff[k] >= 0) ? (base + goff[k]) : zerow;
            async_copy4(g, &dst[k * 256 + tid]);
        }
        const float* wsrc = wt + (size_t)(chunk * CINt + ci) * 2000;
#pragma unroll
        for (int k = 0; k < 2; ++k) {
            int f0 = (k * 256 + tid) * 4;
            const float* g = (f0 < 2000) ? (wsrc + f0) : zerow;
            async_copy16(g, &wbuf[buf][f0]);
        }
    };

    float acc[16];
#pragma unroll
    for (int j = 0; j < 16; ++j) acc[j] = 0.f;

    stage(ci0, 0);
#pragma unroll 1
    for (int i = 0; i < CIPER; ++i) {
        int cur = i & 1;
        __syncthreads();
        if (i + 1 < CIPER) stage(ci0 + i + 1, cur ^ 1);
        const float* shc = &sh[cur][0];
        const float* wb = &wbuf[cur][0];
#pragma unroll 1
        for (int kz = 0; kz < 5; ++kz) {
#pragma unroll 1
            for (int ky = 0; ky < 5; ++ky) {
                const float* rp = shc + ((tz * STRIDE + kz) * LY + ty * STRIDE + ky) * ROWLEN + tx;
                const float* wrow = wb + (kz * 5 + ky) * 5 * 16;
#pragma unroll
                for (int kx = 0; kx < 5; ++kx) {
                    float d = (STRIDE == 2) ? rp[(kx & 1) * LXP + (kx >> 1)] : rp[kx];
#pragma unroll
                    for (int q = 0; q < 4; ++q) {
                        v4f w = *(const v4f*)&wrow[kx * 16 + q * 4];
                        acc[4 * q + 0] = fmaf(d, w.x, acc[4 * q + 0]);
                        acc[4 * q + 1] = fmaf(d, w.y, acc[4 * q + 1]);
                        acc[4 * q + 2] = fmaf(d, w.z, acc[4 * q + 2]);
                        acc[4 * q + 3] = fmaf(d, w.w, acc[4 * q + 3]);
                    }
                }
            }
        }
    }

    int z = tz0 + tz, y = ty0 + ty, x = tx0 + tx;
    size_t sp = ((size_t)z * DOUT + y) * DOUT + x;
    if (CIG > 1) {
#pragma unroll
        for (int j = 0; j < 16; ++j) {
            size_t oidx = (size_t)(b * COUTt + co0 + j) * DOUT * DOUT * DOUT + sp;
            atomicAdd(&out[oidx], acc[j]);
        }
    } else {
        float mval = mask[(size_t)b * DOUT * DOUT * DOUT + sp];
        float vals[16];
#pragma unroll
        for (int j = 0; j < 16; ++j) {
            int co = co0 + j;
            size_t oidx = (size_t)(b * COUTt + co) * DOUT * DOUT * DOUT + sp;
            vals[j] = (acc[j] + bb[co]) * mval;
            out[oidx] = vals[j];
        }
        if (SQW) {
            // channel-last bf16 squared write (for MFMA GDN input)
            bf16x8v s0, s1;
#pragma unroll
            for (int j = 0; j < 8; ++j) {
                s0[j] = (short)f2bf(vals[j] * vals[j]);
                s1[j] = (short)f2bf(vals[j + 8] * vals[j + 8]);
            }
            size_t cl = ((size_t)b * DOUT * DOUT * DOUT + sp) * COUTt + co0;
            *(bf16x8v*)(sqcl + cl) = s0;
            *(bf16x8v*)(sqcl + cl + 8) = s1;
        }
    }
}

// ===== MFMA conv (stride-1): GDN denominators + conv4 =====
// D[m=co][n=voxel] += sum_k W[m][k] * X[k][n] per tap, 32x32x16 bf16 MFMA.
// Data: CL bf16, staged to LDS [voxel][ci16] (32B rows) via width-16 DMA.
// Weights: per-lane divergent global dwordx4 from [cs][nch][tap][n32][kc2][8].
template<int CINt, int COUTt, int Dd, int TZ, int YB, int CIG, int ZSPL>
__global__ __launch_bounds__(256) void mconv_kernel(
    const unsigned short* __restrict__ in,   // CL bf16 [b][z][y][x][CINt]
    const unsigned short* __restrict__ wb,
    const float* __restrict__ zerow,
    float* __restrict__ dout)                // NCDHW fp32, atomicAdd
{
    constexpr int NCH = COUTt / 32;
    constexpr int LZ = TZ + 4, LYH = YB * 4 + 4, LXH = 12;
    constexpr int HV = LZ * LYH * LXH;
    constexpr int UN = 2 * HV;                 // 16B units
    constexpr int NLOAD = (UN + 255) / 256;
    constexpr int NTZ = Dd / TZ, NTY = Dd / (YB * 4), NTX = Dd / 8;
    constexpr int NT = NTZ * NTY * NTX * Bn;
    __shared__ unsigned short lds[NLOAD * 256 * 8];

    int bid = blockIdx.x;
    int tile = bid % NT; int rest = bid / NT;
    int cs = rest % CIG; int zig = rest / CIG;
    int r = tile;
    int tx0 = (r % NTX) * 8; r /= NTX;
    int ty0 = (r % NTY) * (YB * 4); r /= NTY;
    int tz0 = (r % NTZ) * TZ; int b = r / NTZ;

    int tid = threadIdx.x;
    int iz0 = tz0 - 2, iy0 = ty0 - 2, ix0 = tx0 - 2;
#pragma unroll
    for (int k = 0; k < NLOAD; ++k) {
        int u = tid + k * 256;
        int v = u >> 1, half = u & 1;
        int lx = v % LXH; int t = v / LXH;
        int ly = t % LYH, lz = t / LYH;
        int gz = iz0 + lz, gy = iy0 + ly, gx = ix0 + lx;
        bool valid = (v < HV) &&
                     (unsigned)gz < (unsigned)Dd && (unsigned)gy < (unsigned)Dd &&
                     (unsigned)gx < (unsigned)Dd;
        const unsigned short* g = valid
            ? in + ((((size_t)b * Dd + gz) * Dd + gy) * Dd + gx) * CINt + cs * 16 + half * 8
            : (const unsigned short*)zerow;
        async_copy16((const float*)g, (float*)&lds[(size_t)u * 8]);
    }
    __syncthreads();

    int lane = tid & 63, w = tid >> 6;
    int zz = (YB == 1) ? w : (w >> 1);
    int yb = (YB == 1) ? 0 : (w & 1);
    int n = lane & 31, kc = lane >> 5;
    int vy = yb * 4 + (n >> 3), vx = n & 7;

    f32x16v acc[NCH];
#pragma unroll
    for (int c = 0; c < NCH; ++c)
#pragma unroll
        for (int i = 0; i < 16; ++i) acc[c][i] = 0.f;

    int kzlo = (ZSPL == 5) ? zig : 0;
    int kzhi = (ZSPL == 5) ? zig + 1 : 5;
#pragma unroll 1
    for (int kz = kzlo; kz < kzhi; ++kz) {
#pragma unroll 1
        for (int ky = 0; ky < 5; ++ky) {
            int hvrow = ((zz + kz) * LYH + (vy + ky)) * LXH + vx;
#pragma unroll
            for (int kx = 0; kx < 5; ++kx) {
                bf16x8v dfrag = *(const bf16x8v*)&lds[(size_t)(hvrow + kx) * 16 + kc * 8];
                int tap = (kz * 5 + ky) * 5 + kx;
#pragma unroll
                for (int c = 0; c < NCH; ++c) {
                    const unsigned short* wp =
                        wb + (((size_t)(cs * NCH + c) * 125 + tap) << 9) + n * 16 + kc * 8;
                    bf16x8v wfrag = *(const bf16x8v*)wp;
                    acc[c] = __builtin_amdgcn_mfma_f32_32x32x16_bf16(wfrag, dfrag, acc[c], 0, 0, 0);
                }
            }
        }
    }

    int sp = ((tz0 + zz) * Dd + (ty0 + vy)) * Dd + (tx0 + vx);
#pragma unroll
    for (int c = 0; c < NCH; ++c) {
#pragma unroll
        for (int rr = 0; rr < 16; ++rr) {
            int co = c * 32 + (rr & 3) + 8 * (rr >> 2) + 4 * kc;
            atomicAdd(&dout[(size_t)(b * COUTt + co) * Dd * Dd * Dd + sp], acc[c][rr]);
        }
    }
}

// Epilogues
template<int COUTt, int DOUT, bool SQ>
__global__ __launch_bounds__(256) void conv_epi_kernel(float* __restrict__ buf,
        const float* __restrict__ bias, const float* __restrict__ mask,
        unsigned short* __restrict__ sqcl) {
    constexpr int VOX = DOUT * DOUT * DOUT;
    int idx = blockIdx.x * 256 + threadIdx.x;
    if (idx >= Bn * COUTt * VOX) return;
    int sp = idx % VOX;
    int co = (idx / VOX) % COUTt;
    int b = idx / (VOX * COUTt);
    float v = (buf[idx] + bias[co]) * mask[b * VOX + sp];
    buf[idx] = v;
    if (SQ) sqcl[((size_t)b * VOX + sp) * COUTt + co] = f2bf(v * v);
}

template<int COUTt, int DOUT, bool CL>
__global__ __launch_bounds__(256) void gdn_epi_kernel(const float* __restrict__ t,
        const float* __restrict__ den, const float* __restrict__ beta,
        const float* __restrict__ scale, float* __restrict__ y,
        unsigned short* __restrict__ ycl) {
    constexpr int VOX = DOUT * DOUT * DOUT;
    int idx = blockIdx.x * 256 + threadIdx.x;
    if (idx >= Bn * COUTt * VOX) return;
    int sp = idx % VOX;
    int co = (idx / VOX) % COUTt;
    int b = idx / (VOX * COUTt);
    float v = t[idx] * rsqrtf(beta[co] + den[idx]) * scale[b];
    if (CL) ycl[((size_t)b * VOX + sp) * COUTt + co] = f2bf(v);
    else    y[idx] = v;
}

extern "C" void kernel_launch(void* const* d_in, const int* in_sizes, int n_in,
                              void* d_out, int out_size, void* d_ws, size_t ws_size,
                              hipStream_t stream) {
    const float* x_feat = (const float*)d_in[0];
    const float* QF     = (const float*)d_in[2];
    const float* w1 = (const float*)d_in[3];  const float* b1 = (const float*)d_in[4];
    const float* w2 = (const float*)d_in[5];  const float* b2 = (const float*)d_in[6];
    const float* w3 = (const float*)d_in[7];  const float* b3 = (const float*)d_in[8];
    const float* w4 = (const float*)d_in[9];  const float* b4 = (const float*)d_in[10];
    const float* beta1 = (const float*)d_in[11]; const float* gamma1 = (const float*)d_in[12];
    const float* beta2 = (const float*)d_in[13]; const float* gamma2 = (const float*)d_in[14];
    const float* beta3 = (const float*)d_in[15]; const float* gamma3 = (const float*)d_in[16];

    float* out = (float*)d_out;
    float* ws = (float*)d_ws;
    float* cnt   = ws + OFF_CNT;
    float* zerow = ws + OFF_ZERO;
    float* scale = ws + OFF_SCALE;
    float* m1 = ws + OFF_M1;  float* m2 = ws + OFF_M2;  float* m3 = ws + OFF_M3;
    float* t1 = ws + OFF_T1;  float* d1 = ws + OFF_D1;  float* y1 = ws + OFF_Y1;
    float* t2 = ws + OFF_T2;  float* d2 = ws + OFF_D2;  float* y2 = ws + OFF_Y2;
    float* t3 = ws + OFF_T3;  float* d3 = ws + OFF_D3;
    unsigned short* sq1 = (unsigned short*)(ws + OFF_SQ1);
    unsigned short* sq2 = (unsigned short*)(ws + OFF_SQ2);
    unsigned short* sq3 = (unsigned short*)(ws + OFF_SQ3);
    unsigned short* y3c = (unsigned short*)(ws + OFF_Y3C);
    float* w1T = ws + OFF_W1T; float* w2T = ws + OFF_W2T; float* w3T = ws + OFF_W3T;
    unsigned short* wb1 = (unsigned short*)(ws + OFF_WB1);
    unsigned short* wb2 = (unsigned short*)(ws + OFF_WB2);
    unsigned short* wb3 = (unsigned short*)(ws + OFF_WB3);
    unsigned short* wb4 = (unsigned short*)(ws + OFF_WB4);

    hipMemsetAsync(ws, 0, ZERO_END * sizeof(float), stream);
    hipMemsetAsync(out + OUT_X, 0, 131072 * sizeof(float), stream);

    qmean_kernel<<<4, 256, 0, stream>>>(QF, out + OUT_Q, scale);
    mask_pool1_kernel<<<256, 256, 0, stream>>>(x_feat, m1, cnt + 0);
    pool_kernel<<<32, 256, 0, stream>>>(m1, m2, cnt + 2, D1);
    pool_kernel<<<4, 256, 0, stream>>>(m2, m3, cnt + 4, D2);
    writek_kernel<<<1, 64, 0, stream>>>(cnt, out + OUT_K);

    wtrans_all_kernel<<<(FE3 + 255) / 256, 256, 0, stream>>>(w1, w2, w3, ws);
    mwtrans_all_kernel<<<(ME4 + 255) / 256, 256, 0, stream>>>(gamma1, gamma2, gamma3, w4, ws);

    // Stage 1: conv1 VALU (4->32, s2, inline epi + sq1CL) ; GDN1 MFMA ; epi
    conv_tile_kernel<4, 32, 64, 32, 2, 1, true>
        <<<512, 256, 0, stream>>>(x_feat, w1T, b1, m1, zerow, t1, sq1);
    mconv_kernel<32, 32, 32, 4, 1, 2, 1>
        <<<1024, 256, 0, stream>>>(sq1, wb1, zerow, d1);
    gdn_epi_kernel<32, 32, false><<<8192, 256, 0, stream>>>(t1, d1, beta1, scale, y1, nullptr);

    // Stage 2: conv2 VALU (32->64, s2, ci-split x8) ; epi(+sq2) ; GDN2 MFMA ; epi
    conv_tile_kernel<32, 64, 32, 16, 2, 8, false>
        <<<1024, 256, 0, stream>>>(y1, w2T, nullptr, nullptr, zerow, t2, nullptr);
    conv_epi_kernel<64, 16, true><<<2048, 256, 0, stream>>>(t2, b2, m2, sq2);
    mconv_kernel<64, 64, 16, 4, 1, 4, 1>
        <<<256, 256, 0, stream>>>(sq2, wb2, zerow, d2);
    gdn_epi_kernel<64, 16, false><<<2048, 256, 0, stream>>>(t2, d2, beta2, scale, y2, nullptr);

    // Stage 3: conv3 VALU (64->96, s2, ci-split x8) ; epi(+sq3) ; GDN3 MFMA ; epi -> y3 CL bf16
    conv_tile_kernel<64, 96, 16, 8, 2, 8, false>
        <<<192, 256, 0, stream>>>(y2, w3T, nullptr, nullptr, zerow, t3, nullptr);
    conv_epi_kernel<96, 8, true><<<384, 256, 0, stream>>>(t3, b3, m3, sq3);
    mconv_kernel<96, 96, 8, 2, 2, 6, 5>
        <<<240, 256, 0, stream>>>(sq3, wb3, zerow, d3);
    gdn_epi_kernel<96, 8, true><<<384, 256, 0, stream>>>(t3, d3, beta3, scale, nullptr, y3c);

    // Stage 4: conv4 MFMA (96->128, s1) -> out atomics ; final epilogue
    mconv_kernel<96, 128, 8, 2, 2, 6, 5>
        <<<240, 256, 0, stream>>>(y3c, wb4, zerow, out + OUT_X);
    conv_epi_kernel<128, 8, false><<<512, 256, 0, stream>>>(out + OUT_X, b4, m3, nullptr);
}